// Round 8
// baseline (230.252 us; speedup 1.0000x reference)
//
#include <hip/hip_runtime.h>
#include <float.h>
#include <stdint.h>

// Forbid FMA contraction: reference (numpy fp32) rounds every mul/add
// separately; a fused (a1+a2)-iw*ih could flip an iou>0.5 decision.
#pragma clang fp contract(off)

#define NEGV   (-1e9f)
#define THRV   (0.05f)
#define MAXDET 100
#define NB     1152        // score buckets
#define BKBASE 31385       // (bits(0.05f) >> 15)
#define SLABSZ 1024        // LDS chunk capacity
#define CHTGT  512         // target head-chunk size
#define PREB   256         // prefetched boxes for the scan
#define TKCAP  1024        // LDS-resident topk candidates; overflow -> global

__device__ __forceinline__ int bktOf(unsigned u) {
  int v = (int)(u >> 15) - BKBASE;          // monotone in float for s > 0
  return v < 0 ? 0 : (v > NB - 1 ? NB - 1 : v);
}

// Bit-exact "(iou > 0.5)" decision. Certain cases via the two-sided window
// (margin 1e-5 >> max rounding error); ambiguous window does the exact
// reference IEEE divide.
__device__ __forceinline__ bool killpair(
    float qx1, float qy1, float qx2, float qy2, float qa,
    float x1, float y1, float x2, float y2, float a)
{
  const float iw = fminf(qx2, x2) - fmaxf(qx1, x1);
  const float ih = fminf(qy2, y2) - fmaxf(qy1, y1);
  if (iw <= 0.f || ih <= 0.f) return false;
  const float inter = iw * ih;
  const float den = fmaxf((qa + a) - inter, 1e-8f);
  const float i2 = inter + inter;
  if (i2 > den * 1.00001f) return true;
  if (i2 < den * 0.99999f) return false;
  return (inter / den) > 0.5f;
}

// suffix-sum of hist[] (descending bucket layout): hist[bk] becomes the count
// of elements in buckets STRICTLY ABOVE bk. Returns total. Ends barriered.
template<int BT>
__device__ __forceinline__ int suffix_scan(int* hist, int* wtot,
                                           int tid, int lane, int wid) {
  int c0 = 0, c1 = 0, c2 = 0;
  if (tid < NB / 3) {
    c0 = hist[NB - 1 - 3 * tid];
    c1 = hist[NB - 2 - 3 * tid];
    c2 = hist[NB - 3 - 3 * tid];
  }
  const int tsum = c0 + c1 + c2;
  int inc = tsum;
#pragma unroll
  for (int off = 1; off < 64; off <<= 1) {
    const int u = __shfl_up(inc, off, 64);
    if (lane >= off) inc += u;
  }
  if (lane == 63) wtot[wid] = inc;
  __syncthreads();
  int wbase = 0, tot = 0;
#pragma unroll
  for (int w = 0; w < BT / 64; ++w) {
    const int v = wtot[w];
    if (w < wid) wbase += v;
    tot += v;
  }
  const int excl = wbase + inc - tsum;
  if (tid < NB / 3) {
    hist[NB - 1 - 3 * tid] = excl;
    hist[NB - 2 - 3 * tid] = excl + c0;
    hist[NB - 3 - 3 * tid] = excl + c0 + c1;
  }
  __syncthreads();
  return tot;
}

// Batched sorted scan: keep candidate iff no previously-kept box IoU>0.5.
// keys (LDS) descending (score desc, orig idx asc). Returns nk.
template<int BT>
__device__ int run_scan(const unsigned long long* keys, int cn,
                        const float4* __restrict__ bb4,
                        const float4* boxPre, int preN,
                        float4* kboxS, float* kscoreS, float* kareaS,
                        unsigned long long* wkill, unsigned long long* killby,
                        int tid, int lane, int wid)
{
#pragma clang fp contract(off)
  constexpr int NW = BT / 64;
  constexpr int CPW = 64 / NW;
  int nk = 0;
  for (int base = 0; base < cn && nk < MAXDET; base += 64) {
    const int nc = min(64, cn - base);
    const bool valid = lane < nc;
    const int p = base + lane;
    unsigned long long key = 0ull;
    if (valid) key = keys[p];
    const float score = __uint_as_float((unsigned)(key >> 32));
    const int idx = (int)(~(unsigned)key);
    float4 bx = make_float4(0.f, 0.f, 0.f, 0.f);
    if (valid) bx = (p < preN) ? boxPre[p] : bb4[idx];
    const float area = (bx.z - bx.x) * (bx.w - bx.y);

    // vs already-kept: wave w checks kept entries w, w+NW, ...
    bool kill = false;
    for (int e = wid; e < nk; e += NW) {
      const float4 q = kboxS[e];
      kill = kill || killpair(q.x, q.y, q.z, q.w, kareaS[e],
                              bx.x, bx.y, bx.z, bx.w, area);
    }
    {
      const unsigned long long bm = __ballot(valid && kill);
      if (lane == 0) wkill[wid] = bm;
    }
    // in-batch 64x64 matrix: wave w computes columns j = CPW*w .. +CPW-1
    {
      const int cb = wid * CPW;
#pragma unroll
      for (int jj = 0; jj < CPW; ++jj) {
        const int j = cb + jj;
        if (j < nc) {
          const float jx1 = __int_as_float(__builtin_amdgcn_readlane(__float_as_int(bx.x), j));
          const float jy1 = __int_as_float(__builtin_amdgcn_readlane(__float_as_int(bx.y), j));
          const float jx2 = __int_as_float(__builtin_amdgcn_readlane(__float_as_int(bx.z), j));
          const float jy2 = __int_as_float(__builtin_amdgcn_readlane(__float_as_int(bx.w), j));
          const float ja  = __int_as_float(__builtin_amdgcn_readlane(__float_as_int(area), j));
          const bool kij = valid && killpair(jx1, jy1, jx2, jy2, ja,
                                             bx.x, bx.y, bx.z, bx.w, area);
          const unsigned long long bm = __ballot(kij);
          if (lane == 0) killby[j] = bm;
        }
      }
    }
    __syncthreads();                      // wkill/killby ready

    unsigned long long kmask = 0;
#pragma unroll
    for (int w = 0; w < NW; ++w) kmask |= wkill[w];
    unsigned long long alive = ~kmask;
    alive &= (nc >= 64) ? ~0ull : ((1ull << nc) - 1ull);
    const unsigned long long kb = killby[lane];
    for (int j = 0; j < 64; ++j) {
      if ((alive >> j) & 1ull) {
        const unsigned klo = (unsigned)__builtin_amdgcn_readlane((int)(unsigned)kb, j);
        const unsigned khi = (unsigned)__builtin_amdgcn_readlane((int)(unsigned)(kb >> 32), j);
        const unsigned long long km = ((unsigned long long)khi << 32) | klo;
        alive &= ~(km & ((~1ull) << j));  // kill only lower-score bits
      }
    }
    if (wid == 0) {
      const int rank = (int)__popcll(alive & ((1ull << lane) - 1ull));
      if (((alive >> lane) & 1ull) && (nk + rank < MAXDET)) {
        kboxS[nk + rank] = bx;
        kscoreS[nk + rank] = score;
        kareaS[nk + rank] = area;
      }
    }
    nk += min((int)__popcll(alive), MAXDET - nk);
    __syncthreads();
  }
  return nk;
}

// Monotone-cursor selection tail (slow correctness path; never at bench):
// repeatedly take the largest unconsumed key < lastKey, test vs kept list.
template<int BT>
__device__ int selection_tail(const unsigned long long* __restrict__ cd,
                              int cn, unsigned long long lastKey, int nk,
                              const float4* __restrict__ bb4,
                              float4* kboxS, float* kscoreS, float* kareaS,
                              unsigned long long* redS, int* flagS,
                              int tid, int lane, int wid)
{
#pragma clang fp contract(off)
  while (nk < MAXDET) {
    unsigned long long best = 0ull;
    for (int i = tid; i < cn; i += BT) {
      const unsigned long long k = cd[i];
      if (k < lastKey && k > best) best = k;
    }
#pragma unroll
    for (int off = 32; off >= 1; off >>= 1) {
      const unsigned long long o = __shfl_xor(best, off, 64);
      if (o > best) best = o;
    }
    if (lane == 0) redS[wid] = best;
    if (tid == 0) *flagS = 0;
    __syncthreads();
    unsigned long long gbest = redS[0];
#pragma unroll
    for (int w = 1; w < BT / 64; ++w) if (redS[w] > gbest) gbest = redS[w];
    if (gbest == 0ull) break;            // exhausted (real keys are nonzero)
    const int idx = (int)(~(unsigned)gbest);
    const float4 q = bb4[idx];
    const float qa = (q.z - q.x) * (q.w - q.y);
    bool kl = false;
    for (int e = tid; e < nk; e += BT) {
      const float4 kq = kboxS[e];
      kl = kl || killpair(kq.x, kq.y, kq.z, kq.w, kareaS[e],
                          q.x, q.y, q.z, q.w, qa);
    }
    if (kl) atomicOr(flagS, 1);
    __syncthreads();
    const bool killed = (*flagS != 0);
    if (!killed) {
      if (tid == 0) {
        kboxS[nk] = q;
        kscoreS[nk] = __uint_as_float((unsigned)(gbest >> 32));
        kareaS[nk] = qa;
      }
      ++nk;
    }
    __syncthreads();                     // kept + flag reuse safe
    lastKey = gbest;
  }
  return nk;
}

// ---------------------------------------------------------------------------
// Kernel 0 (sweep): one coalesced pass over cls. LDS tile transpose; per
// class-column half-wave: ballot -> one cnt atomic -> compact key write;
// plus per-class bucket histogram via fire-and-forget global atomics.
// ---------------------------------------------------------------------------
__global__ __launch_bounds__(256, 1) void sweep_kernel(
    const float* __restrict__ cls, unsigned long long* __restrict__ cand,
    int* __restrict__ cnt, int* __restrict__ ghist, int N, int C)
{
  __shared__ float tile[32][33];
  const int b = blockIdx.z;
  const int n0 = blockIdx.x * 32, c0 = blockIdx.y * 32;
  const int tx = threadIdx.x, ty = threadIdx.y;   // 32 x 8
  for (int r = ty; r < 32; r += 8) {
    const int n = n0 + r, c = c0 + tx;
    if (n < N && c < C) tile[r][tx] = cls[((size_t)b * N + n) * C + c];
  }
  __syncthreads();
  const int t = ty * 32 + tx;
  const int l = t & 31;                  // n-lane within 32-group
  const int g = t >> 5;                  // group 0..7
  const int lane = t & 63;
#pragma unroll
  for (int pass = 0; pass < 4; ++pass) {
    const int ccol = pass * 8 + g;
    const int c = c0 + ccol;
    const int n = n0 + l;
    const float s = tile[l][ccol];
    const bool pred = (c < C) && (n < N) && (s > THRV);
    const unsigned long long bal = __ballot(pred);
    const unsigned hm = (unsigned)(bal >> (lane & 32));   // this half's mask
    const int npass = __popc(hm);
    int base = 0;
    if ((l == 0) && npass) base = atomicAdd(&cnt[b * C + c], npass);
    base = __shfl(base, lane & 32, 64);
    if (pred) {
      const unsigned u = __float_as_uint(s);
      const int rank = __popc(hm & ((1u << l) - 1u));
      const size_t bcIdx = (size_t)(b * C + c);
      cand[bcIdx * N + base + rank] =
          ((unsigned long long)u << 32) | (unsigned)(~n);
      atomicAdd(&ghist[bcIdx * NB + bktOf(u)], 1);   // fire-and-forget
    }
  }
}

// ---------------------------------------------------------------------------
// Kernel 1 (nms): per-(image,class). Histogram precomputed by sweep; one
// coalesced pass over candidates scatters the head chunk into LDS; rank-sort;
// box prefetch; batched sorted scan. Selection tail for pathological inputs.
// ---------------------------------------------------------------------------
template<int BT>
__global__ __launch_bounds__(BT, 1) void nms_kernel(
    const float* __restrict__ boxes,
    const unsigned long long* __restrict__ cand,
    const int* __restrict__ cnt, const int* __restrict__ ghist,
    float* __restrict__ ksc, float* __restrict__ kbx, int N, int C)
{
#pragma clang fp contract(off)
  const int bc = blockIdx.x;
  const int cn = cnt[bc];
  const int tid = threadIdx.x, lane = tid & 63, wid = tid >> 6;
  const unsigned long long* cd = cand + (size_t)bc * N;
  const float4* bb4 = (const float4*)(boxes + (size_t)(bc / C) * N * 4);

  __shared__ int hist[NB];
  __shared__ int wtot[BT / 64];
  __shared__ unsigned long long slab[SLABSZ];
  __shared__ unsigned long long sorted[SLABSZ];
  __shared__ float4 boxPre[PREB];
  __shared__ float4 kboxS[MAXDET];
  __shared__ float kscoreS[MAXDET], kareaS[MAXDET];
  __shared__ unsigned long long wkill[BT / 64], killby[64];
  __shared__ unsigned long long redS[BT / 64];
  __shared__ int flagS;
  __shared__ int bkLoS;

  for (int i = tid; i < NB; i += BT) hist[i] = ghist[(size_t)bc * NB + i];
  if (tid == 0) bkLoS = -1;
  __syncthreads();
  suffix_scan<BT>(hist, wtot, tid, lane, wid);
  for (int bk = tid; bk < NB; bk += BT)
    if (hist[bk] >= CHTGT) atomicMax(&bkLoS, bk);
  __syncthreads();
  const int bkLo = bkLoS;
  const int chunkCnt = (bkLo >= 0) ? hist[bkLo] : cn;   // head is a prefix

  int nk = 0;
  if (chunkCnt <= SLABSZ) {
    // scatter head (buckets > bkLo); hist[bk] is the in-chunk start pos
    for (int i = tid; i < cn; i += BT) {
      const unsigned long long k = cd[i];
      const int bk = bktOf((unsigned)(k >> 32));
      if (bk > bkLo) slab[atomicAdd(&hist[bk], 1)] = k;
    }
    __syncthreads();
    // rank-by-count sort (keys unique; broadcast LDS reads, no divergence)
    for (int e = tid; e < chunkCnt; e += BT) {
      const unsigned long long k = slab[e];
      int r = 0;
      for (int j = 0; j < chunkCnt; ++j) r += (slab[j] > k) ? 1 : 0;
      sorted[r] = k;
    }
    __syncthreads();
    const int preN = min(chunkCnt, PREB);
    for (int e = tid; e < preN; e += BT)
      boxPre[e] = bb4[(int)(~(unsigned)sorted[e])];
    __syncthreads();
    nk = run_scan<BT>(sorted, chunkCnt, bb4, boxPre, preN,
                      kboxS, kscoreS, kareaS, wkill, killby, tid, lane, wid);
    if (nk < MAXDET && chunkCnt < cn)
      nk = selection_tail<BT>(cd, cn, sorted[chunkCnt - 1], nk, bb4,
                              kboxS, kscoreS, kareaS, redS, &flagS,
                              tid, lane, wid);
  } else {
    // degenerate (giant single bucket): full selection from scratch
    nk = selection_tail<BT>(cd, cn, ~0ull, 0, bb4,
                            kboxS, kscoreS, kareaS, redS, &flagS,
                            tid, lane, wid);
  }

  // emit
  float* ko  = ksc + (size_t)bc * MAXDET;
  float* kbo = kbx + (size_t)bc * MAXDET * 4;
  for (int e = tid; e < MAXDET; e += BT) {
    if (e < nk) {
      const float4 q = kboxS[e];
      ko[e] = kscoreS[e];
      kbo[e * 4 + 0] = q.x; kbo[e * 4 + 1] = q.y;
      kbo[e * 4 + 2] = q.z; kbo[e * 4 + 3] = q.w;
    } else {
      ko[e] = NEGV;
      kbo[e * 4 + 0] = 0.f; kbo[e * 4 + 1] = 0.f;
      kbo[e * 4 + 2] = 0.f; kbo[e * 4 + 3] = 0.f;
    }
  }
}

// ---------------------------------------------------------------------------
// Kernel 2 (topk): per-image top-100 via radix-select over score buckets:
// histogram -> threshold bucket -> compact ~107 candidates -> rank-by-count.
// Key (score_bits<<32 | ~flat_idx) == lax.top_k (value desc, idx asc).
// ---------------------------------------------------------------------------
template<int BT>
__global__ __launch_bounds__(BT, 1) void topk_kernel(
    const float* __restrict__ ksc, const float* __restrict__ kbx,
    unsigned long long* __restrict__ gcand_all,
    float* __restrict__ out, int B, int C)
{
  const int b = blockIdx.x;
  const int tid = threadIdx.x, lane = tid & 63, wid = tid >> 6;
  const int T = C * MAXDET;
  const float* s0 = ksc + (size_t)b * T;
  unsigned long long* gc = gcand_all + (size_t)b * T;   // overflow only
  float* ob = out;                              // [B][100][4]
  float* os = out + (size_t)B * MAXDET * 4;     // [B][100]
  float* ol = os + (size_t)B * MAXDET;          // [B][100] labels as float

  __shared__ int hist[NB];
  __shared__ int wtot[BT / 64];
  __shared__ unsigned long long candS[TKCAP];
  __shared__ int tBs, cposS;

  for (int i = tid; i < NB; i += BT) hist[i] = 0;
  if (tid == 0) { cposS = 0; tBs = 0; }
  __syncthreads();
  for (int f = tid; f < T; f += BT) {
    const float s = s0[f];
    if (s > THRV) atomicAdd(&hist[bktOf(__float_as_uint(s))], 1);
  }
  __syncthreads();
  suffix_scan<BT>(hist, wtot, tid, lane, wid);
  for (int bk = tid; bk < NB; bk += BT)
    if (hist[bk] < MAXDET && (bk == 0 || hist[bk - 1] >= MAXDET)) tBs = bk;
  __syncthreads();
  const int t = tBs;
  for (int f = tid; f < T; f += BT) {
    const float s = s0[f];
    if (s > THRV) {
      const unsigned u = __float_as_uint(s);
      if (bktOf(u) >= t) {
        const int p = atomicAdd(&cposS, 1);
        const unsigned long long key =
            ((unsigned long long)u << 32) | (unsigned)(~f);
        if (p < TKCAP) candS[p] = key; else gc[p] = key;
      }
    }
  }
  __syncthreads();
  const int nc = cposS;
  const int nw = min(nc, MAXDET);
  for (int s2 = nw + tid; s2 < MAXDET; s2 += BT) {
    float* od = ob + ((size_t)b * MAXDET + s2) * 4;
    od[0] = -1.f; od[1] = -1.f; od[2] = -1.f; od[3] = -1.f;
    os[(size_t)b * MAXDET + s2] = -1.f;
    ol[(size_t)b * MAXDET + s2] = -1.f;
  }
  for (int e = tid; e < nc; e += BT) {
    const unsigned long long k = (e < TKCAP) ? candS[e] : gc[e];
    int rank = 0;
    for (int j = 0; j < nc; ++j) {
      const unsigned long long o = (j < TKCAP) ? candS[j] : gc[j];
      rank += (o > k) ? 1 : 0;
    }
    if (rank < MAXDET) {
      const int f = (int)(~(unsigned)k);
      const float sc = __uint_as_float((unsigned)(k >> 32));
      const float* bp = kbx + ((size_t)b * T + f) * 4;
      float* od = ob + ((size_t)b * MAXDET + rank) * 4;
      od[0] = bp[0]; od[1] = bp[1]; od[2] = bp[2]; od[3] = bp[3];
      os[(size_t)b * MAXDET + rank] = sc;
      ol[(size_t)b * MAXDET + rank] = (float)(f / MAXDET);
    }
  }
}

extern "C" void kernel_launch(void* const* d_in, const int* in_sizes, int n_in,
                              void* d_out, int out_size, void* d_ws, size_t ws_size,
                              hipStream_t stream) {
  const float* boxes = (const float*)d_in[0];  // (B, N, 4) f32
  const float* cls   = (const float*)d_in[1];  // (B, N, C) f32
  const int B = out_size / (MAXDET * 6);       // 4 box + 1 score + 1 label
  const int N = in_sizes[0] / (B * 4);
  const int C = in_sizes[1] / (B * N);

  char* ws = (char*)d_ws;
  unsigned long long* cand = (unsigned long long*)ws;
  ws += (size_t)B * C * N * 8;                                 // candidate keys
  float* kbx = (float*)ws;  ws += (size_t)B * C * MAXDET * 16; // kept boxes
  float* ksc = (float*)ws;  ws += (size_t)B * C * MAXDET * 4;  // kept scores
  unsigned long long* gcand = (unsigned long long*)ws;
  ws += (size_t)B * C * MAXDET * 8;                            // topk overflow
  int* ghist = (int*)ws; ws += (size_t)B * C * NB * 4;         // class hists
  int* cnt = (int*)ws;                                         // alive counts

  // zero ghist + cnt in one contiguous memset
  hipMemsetAsync(ghist, 0, (size_t)B * C * NB * 4 + (size_t)B * C * 4, stream);
  sweep_kernel<<<dim3((N + 31) / 32, (C + 31) / 32, B), dim3(32, 8),
                 0, stream>>>(cls, cand, cnt, ghist, N, C);
  nms_kernel<512><<<dim3(B * C), dim3(512), 0, stream>>>(
      boxes, cand, cnt, ghist, ksc, kbx, N, C);
  topk_kernel<512><<<dim3(B), dim3(512), 0, stream>>>(
      ksc, kbx, gcand, (float*)d_out, B, C);
}

// Round 9
// 169.192 us; speedup vs baseline: 1.3609x; 1.3609x over previous
//
#include <hip/hip_runtime.h>
#include <float.h>
#include <stdint.h>

// Forbid FMA contraction: reference (numpy fp32) rounds every mul/add
// separately; a fused (a1+a2)-iw*ih could flip an iou>0.5 decision.
#pragma clang fp contract(off)

typedef unsigned long long ull;

#define NEGV   (-1e9f)
#define THRV   (0.05f)
#define MAXDET 100
#define NB     1152        // score buckets
#define BKBASE 31385       // (bits(0.05f) >> 15)
#define SLABSZ 1024        // LDS chunk capacity
#define CHTGT  512         // target head-chunk size
#define TKCAP  1024        // LDS-resident topk candidates; overflow -> global
#define BT     512

__device__ __forceinline__ int bktOf(unsigned u) {
  int v = (int)(u >> 15) - BKBASE;          // monotone in float for s > 0
  return v < 0 ? 0 : (v > NB - 1 ? NB - 1 : v);
}

// Bit-exact "(iou > 0.5)" decision. Certain cases via the two-sided window
// (margin 1e-5 >> max rounding error); ambiguous window does the exact
// reference IEEE divide.
__device__ __forceinline__ bool killpair(
    float qx1, float qy1, float qx2, float qy2, float qa,
    float x1, float y1, float x2, float y2, float a)
{
  const float iw = fminf(qx2, x2) - fmaxf(qx1, x1);
  const float ih = fminf(qy2, y2) - fmaxf(qy1, y1);
  if (iw <= 0.f || ih <= 0.f) return false;
  const float inter = iw * ih;
  const float den = fmaxf((qa + a) - inter, 1e-8f);
  const float i2 = inter + inter;
  if (i2 > den * 1.00001f) return true;
  if (i2 < den * 0.99999f) return false;
  return (inter / den) > 0.5f;
}

// suffix-sum of hist[] (descending bucket layout): hist[bk] becomes the count
// of elements in buckets STRICTLY ABOVE bk. Returns total. Ends barriered.
__device__ __forceinline__ int suffix_scan(int* hist, int* wtot,
                                           int tid, int lane, int wid) {
  int c0 = 0, c1 = 0, c2 = 0;
  if (tid < NB / 3) {
    c0 = hist[NB - 1 - 3 * tid];
    c1 = hist[NB - 2 - 3 * tid];
    c2 = hist[NB - 3 - 3 * tid];
  }
  const int tsum = c0 + c1 + c2;
  int inc = tsum;
#pragma unroll
  for (int off = 1; off < 64; off <<= 1) {
    const int u = __shfl_up(inc, off, 64);
    if (lane >= off) inc += u;
  }
  if (lane == 63) wtot[wid] = inc;
  __syncthreads();
  int wbase = 0, tot = 0;
#pragma unroll
  for (int w = 0; w < BT / 64; ++w) {
    const int v = wtot[w];
    if (w < wid) wbase += v;
    tot += v;
  }
  const int excl = wbase + inc - tsum;
  if (tid < NB / 3) {
    hist[NB - 1 - 3 * tid] = excl;
    hist[NB - 2 - 3 * tid] = excl + c0;
    hist[NB - 3 - 3 * tid] = excl + c0 + c1;
  }
  __syncthreads();
  return tot;
}

// Batched sorted scan: keep candidate iff no previously-kept box IoU>0.5.
// keys (LDS) descending (score desc, orig idx asc). Returns nk.
__device__ int run_scan(const ull* keys, int cn,
                        const float4* __restrict__ bb4,
                        const float4* boxPre, int preN,
                        float4* kboxS, float* kscoreS, float* kareaS,
                        ull* wkill, ull* killby,
                        int tid, int lane, int wid)
{
#pragma clang fp contract(off)
  constexpr int NW = BT / 64;
  constexpr int CPW = 64 / NW;
  int nk = 0;
  for (int base = 0; base < cn && nk < MAXDET; base += 64) {
    const int nc = min(64, cn - base);
    const bool valid = lane < nc;
    const int p = base + lane;
    ull key = 0ull;
    if (valid) key = keys[p];
    const float score = __uint_as_float((unsigned)(key >> 32));
    const int idx = (int)(~(unsigned)key);
    float4 bx = make_float4(0.f, 0.f, 0.f, 0.f);
    if (valid) bx = (p < preN) ? boxPre[p] : bb4[idx];
    const float area = (bx.z - bx.x) * (bx.w - bx.y);

    // vs already-kept: wave w checks kept entries w, w+NW, ...
    bool kill = false;
    for (int e = wid; e < nk; e += NW) {
      const float4 q = kboxS[e];
      kill = kill || killpair(q.x, q.y, q.z, q.w, kareaS[e],
                              bx.x, bx.y, bx.z, bx.w, area);
    }
    {
      const ull bm = __ballot(valid && kill);
      if (lane == 0) wkill[wid] = bm;
    }
    // in-batch 64x64 matrix: wave w computes columns j = CPW*w .. +CPW-1
    {
      const int cb = wid * CPW;
#pragma unroll
      for (int jj = 0; jj < CPW; ++jj) {
        const int j = cb + jj;
        if (j < nc) {
          const float jx1 = __int_as_float(__builtin_amdgcn_readlane(__float_as_int(bx.x), j));
          const float jy1 = __int_as_float(__builtin_amdgcn_readlane(__float_as_int(bx.y), j));
          const float jx2 = __int_as_float(__builtin_amdgcn_readlane(__float_as_int(bx.z), j));
          const float jy2 = __int_as_float(__builtin_amdgcn_readlane(__float_as_int(bx.w), j));
          const float ja  = __int_as_float(__builtin_amdgcn_readlane(__float_as_int(area), j));
          const bool kij = valid && killpair(jx1, jy1, jx2, jy2, ja,
                                             bx.x, bx.y, bx.z, bx.w, area);
          const ull bm = __ballot(kij);
          if (lane == 0) killby[j] = bm;
        }
      }
    }
    __syncthreads();                      // wkill/killby ready

    ull kmask = 0;
#pragma unroll
    for (int w = 0; w < NW; ++w) kmask |= wkill[w];
    ull alive = ~kmask;
    alive &= (nc >= 64) ? ~0ull : ((1ull << nc) - 1ull);
    const ull kb = killby[lane];
    for (int j = 0; j < 64; ++j) {
      if ((alive >> j) & 1ull) {
        const unsigned klo = (unsigned)__builtin_amdgcn_readlane((int)(unsigned)kb, j);
        const unsigned khi = (unsigned)__builtin_amdgcn_readlane((int)(unsigned)(kb >> 32), j);
        const ull km = ((ull)khi << 32) | klo;
        alive &= ~(km & ((~1ull) << j));  // kill only lower-score bits
      }
    }
    if (wid == 0) {
      const int rank = (int)__popcll(alive & ((1ull << lane) - 1ull));
      if (((alive >> lane) & 1ull) && (nk + rank < MAXDET)) {
        kboxS[nk + rank] = bx;
        kscoreS[nk + rank] = score;
        kareaS[nk + rank] = area;
      }
    }
    nk += min((int)__popcll(alive), MAXDET - nk);
    __syncthreads();
  }
  return nk;
}

// Monotone-cursor selection tail re-scanning the strided cls column.
// Slow correctness path; never runs at bench statistics.
__device__ int selection_tail(const float* __restrict__ col, int N, int C,
                              ull lastKey, int nk,
                              const float4* __restrict__ bb4,
                              float4* kboxS, float* kscoreS, float* kareaS,
                              ull* redS, int* flagS,
                              int tid, int lane, int wid)
{
#pragma clang fp contract(off)
  while (nk < MAXDET) {
    ull best = 0ull;
    for (int i = tid; i < N; i += BT) {
      const float s = col[(size_t)i * C];
      if (s > THRV) {
        const ull k = ((ull)__float_as_uint(s) << 32) | (unsigned)(~i);
        if (k < lastKey && k > best) best = k;
      }
    }
#pragma unroll
    for (int off = 32; off >= 1; off >>= 1) {
      const ull o = __shfl_xor(best, off, 64);
      if (o > best) best = o;
    }
    if (lane == 0) redS[wid] = best;
    if (tid == 0) *flagS = 0;
    __syncthreads();
    ull gbest = redS[0];
#pragma unroll
    for (int w = 1; w < BT / 64; ++w) if (redS[w] > gbest) gbest = redS[w];
    if (gbest == 0ull) break;            // exhausted (real keys are nonzero)
    const int idx = (int)(~(unsigned)gbest);
    const float4 q = bb4[idx];
    const float qa = (q.z - q.x) * (q.w - q.y);
    bool kl = false;
    for (int e = tid; e < nk; e += BT) {
      const float4 kq = kboxS[e];
      kl = kl || killpair(kq.x, kq.y, kq.z, kq.w, kareaS[e],
                          q.x, q.y, q.z, q.w, qa);
    }
    if (kl) atomicOr(flagS, 1);
    __syncthreads();
    const bool killed = (*flagS != 0);
    if (!killed) {
      if (tid == 0) {
        kboxS[nk] = q;
        kscoreS[nk] = __uint_as_float((unsigned)(gbest >> 32));
        kareaS[nk] = qa;
      }
      ++nk;
    }
    __syncthreads();
    lastKey = gbest;
  }
  return nk;
}

__device__ __forceinline__ unsigned agent_load_u32(const float* p) {
  return __hip_atomic_load((const unsigned*)p, __ATOMIC_RELAXED,
                           __HIP_MEMORY_SCOPE_AGENT);
}

// ---------------------------------------------------------------------------
// Single fused kernel. One block per (image, class):
//   strided column read -> hist -> head-chunk radix select -> rank-sort ->
//   batched sorted scan -> emit kept list. The last-finishing block of each
//   image (device-scope counter) then runs the per-image top-100 radix select.
// ---------------------------------------------------------------------------
__global__ __launch_bounds__(BT, 1) void nms_fused(
    const float* __restrict__ boxes, const float* __restrict__ cls,
    float* __restrict__ ksc, float* __restrict__ kbx,
    ull* __restrict__ gcand, unsigned* __restrict__ done,
    float* __restrict__ out, int N, int C, int B)
{
#pragma clang fp contract(off)
  const int bc = blockIdx.x;
  const int b = bc / C, c = bc % C;
  const int tid = threadIdx.x, lane = tid & 63, wid = tid >> 6;
  const float* col = cls + (size_t)b * N * C + c;
  const float4* bb4 = (const float4*)(boxes + (size_t)b * N * 4);

  __shared__ int hist[NB];
  __shared__ int wtot[BT / 64];
  __shared__ ull slab[SLABSZ];
  __shared__ ull sorted[SLABSZ];              // reused as topk candidate slab
  __shared__ float4 boxPre[SLABSZ];
  __shared__ float4 kboxS[MAXDET];
  __shared__ float kscoreS[MAXDET], kareaS[MAXDET];
  __shared__ ull wkill[BT / 64], killby[64], redS[BT / 64];
  __shared__ int flagS, bkLoS, tBs, cposS, lastS;

  // ---- Phase A: histogram of alive scores (strided column read #1) ----
  for (int i = tid; i < NB; i += BT) hist[i] = 0;
  if (tid == 0) bkLoS = -1;
  __syncthreads();
  for (int i = tid; i < N; i += BT) {
    const float s = col[(size_t)i * C];
    if (s > THRV) atomicAdd(&hist[bktOf(__float_as_uint(s))], 1);
  }
  __syncthreads();
  const int cn = suffix_scan(hist, wtot, tid, lane, wid);
  for (int bk = tid; bk < NB; bk += BT)
    if (hist[bk] >= CHTGT) atomicMax(&bkLoS, bk);
  __syncthreads();
  const int bkLo = bkLoS;
  const int chunkCnt = (bkLo >= 0) ? hist[bkLo] : cn;   // head is a prefix

  int nk = 0;
  if (cn > 0) {
    if (chunkCnt <= SLABSZ) {
      // ---- Phase B: scatter head (buckets > bkLo); column read #2 ----
      for (int i = tid; i < N; i += BT) {
        const float s = col[(size_t)i * C];
        if (s > THRV) {
          const unsigned u = __float_as_uint(s);
          const int bk = bktOf(u);
          if (bk > bkLo)
            slab[atomicAdd(&hist[bk], 1)] = ((ull)u << 32) | (unsigned)(~i);
        }
      }
      __syncthreads();
      // rank-by-count sort (keys unique; broadcast LDS reads)
      for (int e = tid; e < chunkCnt; e += BT) {
        const ull k = slab[e];
        int r = 0;
        for (int j = 0; j < chunkCnt; ++j) r += (slab[j] > k) ? 1 : 0;
        sorted[r] = k;
      }
      __syncthreads();
      for (int e = tid; e < chunkCnt; e += BT)
        boxPre[e] = bb4[(int)(~(unsigned)sorted[e])];
      __syncthreads();
      nk = run_scan(sorted, chunkCnt, bb4, boxPre, chunkCnt,
                    kboxS, kscoreS, kareaS, wkill, killby, tid, lane, wid);
      if (nk < MAXDET && chunkCnt < cn)
        nk = selection_tail(col, N, C, sorted[chunkCnt - 1], nk, bb4,
                            kboxS, kscoreS, kareaS, redS, &flagS,
                            tid, lane, wid);
    } else {
      // degenerate (giant single bucket): full selection from scratch
      nk = selection_tail(col, N, C, ~0ull, 0, bb4,
                          kboxS, kscoreS, kareaS, redS, &flagS,
                          tid, lane, wid);
    }
  }

  // ---- emit kept list ----
  float* ko  = ksc + (size_t)bc * MAXDET;
  float* kbo = kbx + (size_t)bc * MAXDET * 4;
  for (int e = tid; e < MAXDET; e += BT) {
    if (e < nk) {
      const float4 q = kboxS[e];
      ko[e] = kscoreS[e];
      kbo[e * 4 + 0] = q.x; kbo[e * 4 + 1] = q.y;
      kbo[e * 4 + 2] = q.z; kbo[e * 4 + 3] = q.w;
    } else {
      ko[e] = NEGV;
      kbo[e * 4 + 0] = 0.f; kbo[e * 4 + 1] = 0.f;
      kbo[e * 4 + 2] = 0.f; kbo[e * 4 + 3] = 0.f;
    }
  }

  // ---- completion handshake: last block of image b runs topk ----
  __threadfence();                 // flush this thread's stores to agent scope
  __syncthreads();                 // all threads' stores drained + fenced
  if (tid == 0) {
    const unsigned old = __hip_atomic_fetch_add(
        &done[b], 1u, __ATOMIC_ACQ_REL, __HIP_MEMORY_SCOPE_AGENT);
    lastS = (old == (unsigned)(C - 1)) ? 1 : 0;
  }
  __syncthreads();
  if (!lastS) return;

  // ======================= per-image top-100 =======================
  const int T = C * MAXDET;
  const float* s0 = ksc + (size_t)b * T;
  ull* gc = gcand + (size_t)b * T;              // overflow only
  float* ob = out;                              // [B][100][4]
  float* os = out + (size_t)B * MAXDET * 4;     // [B][100]
  float* ol = os + (size_t)B * MAXDET;          // [B][100] labels as float

  for (int i = tid; i < NB; i += BT) hist[i] = 0;
  if (tid == 0) { cposS = 0; tBs = 0; }
  __syncthreads();
  for (int f = tid; f < T; f += BT) {
    const unsigned u = agent_load_u32(&s0[f]);
    if (__uint_as_float(u) > THRV) atomicAdd(&hist[bktOf(u)], 1);
  }
  __syncthreads();
  suffix_scan(hist, wtot, tid, lane, wid);
  for (int bk = tid; bk < NB; bk += BT)
    if (hist[bk] < MAXDET && (bk == 0 || hist[bk - 1] >= MAXDET)) tBs = bk;
  __syncthreads();
  const int t = tBs;
  for (int f = tid; f < T; f += BT) {
    const unsigned u = agent_load_u32(&s0[f]);
    if (__uint_as_float(u) > THRV && bktOf(u) >= t) {
      const int p = atomicAdd(&cposS, 1);
      const ull key = ((ull)u << 32) | (unsigned)(~f);
      if (p < TKCAP) sorted[p] = key; else gc[p] = key;
    }
  }
  __syncthreads();
  const int nc = cposS;
  const int nw = min(nc, MAXDET);
  for (int s2 = nw + tid; s2 < MAXDET; s2 += BT) {
    float* od = ob + ((size_t)b * MAXDET + s2) * 4;
    od[0] = -1.f; od[1] = -1.f; od[2] = -1.f; od[3] = -1.f;
    os[(size_t)b * MAXDET + s2] = -1.f;
    ol[(size_t)b * MAXDET + s2] = -1.f;
  }
  for (int e = tid; e < nc; e += BT) {
    const ull k = (e < TKCAP) ? sorted[e] : gc[e];
    int rank = 0;
    for (int j = 0; j < nc; ++j) {
      const ull o = (j < TKCAP) ? sorted[j] : gc[j];
      rank += (o > k) ? 1 : 0;
    }
    if (rank < MAXDET) {
      const int f = (int)(~(unsigned)k);
      const float sc = __uint_as_float((unsigned)(k >> 32));
      const float* bp = kbx + ((size_t)b * T + f) * 4;
      float* od = ob + ((size_t)b * MAXDET + rank) * 4;
      od[0] = __uint_as_float(agent_load_u32(&bp[0]));
      od[1] = __uint_as_float(agent_load_u32(&bp[1]));
      od[2] = __uint_as_float(agent_load_u32(&bp[2]));
      od[3] = __uint_as_float(agent_load_u32(&bp[3]));
      os[(size_t)b * MAXDET + rank] = sc;
      ol[(size_t)b * MAXDET + rank] = (float)(f / MAXDET);
    }
  }
}

extern "C" void kernel_launch(void* const* d_in, const int* in_sizes, int n_in,
                              void* d_out, int out_size, void* d_ws, size_t ws_size,
                              hipStream_t stream) {
  const float* boxes = (const float*)d_in[0];  // (B, N, 4) f32
  const float* cls   = (const float*)d_in[1];  // (B, N, C) f32
  const int B = out_size / (MAXDET * 6);       // 4 box + 1 score + 1 label
  const int N = in_sizes[0] / (B * 4);
  const int C = in_sizes[1] / (B * N);

  char* ws = (char*)d_ws;
  ull* gcand = (ull*)ws;   ws += (size_t)B * C * MAXDET * 8;   // topk overflow
  float* kbx = (float*)ws; ws += (size_t)B * C * MAXDET * 16;  // kept boxes
  float* ksc = (float*)ws; ws += (size_t)B * C * MAXDET * 4;   // kept scores
  unsigned* done = (unsigned*)ws;                              // per-image ctr

  hipMemsetAsync(done, 0, (size_t)B * 4, stream);
  nms_fused<<<dim3(B * C), dim3(BT), 0, stream>>>(
      boxes, cls, ksc, kbx, gcand, done, (float*)d_out, N, C, B);
}